// Round 11
// baseline (159.915 us; speedup 1.0000x reference)
//
#include <hip/hip_runtime.h>
#include <cstdint>
#include <cstddef>

#define B_ 16
#define T_ 8192
#define D_ 256
#define U_ 256

typedef __attribute__((ext_vector_type(8))) short bf16x8;
typedef __attribute__((ext_vector_type(16))) float f32x16;
typedef __attribute__((ext_vector_type(4))) unsigned int u32x4;

#define VMCNT(N) asm volatile("s_waitcnt vmcnt(" #N ")" ::: "memory")

__device__ inline f32x16 mfma32(bf16x8 a, bf16x8 b, f32x16 c) {
    return __builtin_amdgcn_mfma_f32_32x32x16_bf16(a, b, c, 0, 0, 0);
}

// pack high-16 (truncated bf16) of two fp32 into one u32: [y_hi16 : x_hi16]
__device__ inline unsigned int pack2_hi(float x, float y) {
    return __builtin_amdgcn_perm(__float_as_uint(y), __float_as_uint(x), 0x07060302u);
}
__device__ inline float lo_part(float x) {
    return x - __uint_as_float(__float_as_uint(x) & 0xffff0000u);
}

// convert 8 fp32 (two float4s) -> bf16 hi/lo fragments (truncation split)
__device__ inline void cvt8v(const float4 a, const float4 b, bf16x8& hi, bf16x8& lo) {
    u32x4 h, l;
    h[0] = pack2_hi(a.x, a.y);
    h[1] = pack2_hi(a.z, a.w);
    h[2] = pack2_hi(b.x, b.y);
    h[3] = pack2_hi(b.z, b.w);
    l[0] = pack2_hi(lo_part(a.x), lo_part(a.y));
    l[1] = pack2_hi(lo_part(a.z), lo_part(a.w));
    l[2] = pack2_hi(lo_part(b.x), lo_part(b.y));
    l[3] = pack2_hi(lo_part(b.z), lo_part(b.w));
    hi = __builtin_bit_cast(bf16x8, h);
    lo = __builtin_bit_cast(bf16x8, l);
}

// ---------------- Kernel 0: W1 [d][u] -> W1^T bf16 hi/lo [u][d] ----------------
__global__ __launch_bounds__(256) void prep_w1t_kernel(const float* __restrict__ W1,
                                                       unsigned short* __restrict__ hi,
                                                       unsigned short* __restrict__ lo) {
    const int idx = blockIdx.x * 256 + threadIdx.x;   // 0..65535
    const int d = idx >> 8;
    const int u = idx & 255;
    const float x = W1[idx];
    const unsigned int xb = __float_as_uint(x);
    const unsigned short h = (unsigned short)(xb >> 16);
    const float lf = x - __uint_as_float(xb & 0xffff0000u);
    const unsigned short lo16 = (unsigned short)(__float_as_uint(lf) >> 16);
    hi[u * D_ + d] = h;
    lo[u * D_ + d] = lo16;
}

// ---------------- Kernel 1: hidden = query @ W2  -> [B, U] ----------------
__global__ __launch_bounds__(256) void hidden_kernel(const float* __restrict__ q,
                                                     const float* __restrict__ W2,
                                                     float* __restrict__ hidden) {
    const int b = blockIdx.x;
    const int u = threadIdx.x;
    __shared__ float qs[D_];
    qs[u] = q[b * D_ + u];
    __syncthreads();
    float acc = 0.f;
#pragma unroll 8
    for (int d = 0; d < D_; ++d)
        acc += qs[d] * W2[d * U_ + u];
    hidden[b * U_ + u] = acc;
}

// ---------------- Kernel 2: fused scores + chunk softmax + chunk context ----------
// Block: 256 thr = 4 waves, 128 t-rows x 256 u. U-SPLIT: wave w owns ALL 128 rows
// x u in [w*64, w*64+64) -> each B uf-tile read by exactly ONE wave (4x less LDS
// traffic than t-split; MFMA:ds_read = 12:1) and B slices are WAVE-PRIVATE ->
// the k-loop has NO barriers. Per-wave ordering via counted vmcnt only:
//   iter k: VMCNT(16) [retires own stage(k), 8 ops; A(k) 16 loads keep flying,
//   compiler waits at cvt] -> stage(k+1) -> {per rt,h: cvt A -> reload A(k+1)
//   after last use -> 6 MFMA_32x32x16 per (rt,h)}.
// A loaded per-wave from global (4x intra-block redundancy, L2-absorbed).
// MFMA shape 32x32x16 (2382 TF ceiling vs 2075 for 16x16).
// A frag (lane l): value[t0+rt*32+(l&31)][k0+h*16+(l>>5)*8 + 0..7]
// B frag (lane l): w1t[(w*64+ct*32+(l&31))*256 + k0+h*16+(l>>5)*8 .. +8]  (lane-ordered LDS)
// C (lane l, reg r): keys[rt*32 + (r&3)+8*(r>>2)+4*(l>>5)][w*64+ct*32+(l&31)]  [m74/m101]
__global__ __launch_bounds__(256, 2) void scores_ctx_kernel(
        const float* __restrict__ value,
        const unsigned short* __restrict__ w1t_hi,
        const unsigned short* __restrict__ w1t_lo,
        const float* __restrict__ Vv,
        const float* __restrict__ hidden,
        float* __restrict__ partial,
        float* __restrict__ mstat,
        float* __restrict__ lstat) {
    const int b    = blockIdx.y;
    const int bx   = blockIdx.x;
    const int t0   = bx * 128;
    const int tid  = threadIdx.x;
    const int w    = tid >> 6;
    const int lane = tid & 63;
    const int lr   = lane & 31;
    const int lk   = lane >> 5;

    __shared__ unsigned short bB[2][4][2][2][2][512];  // [buf][wave][hi/lo][ct][h][lane*8] = 64 KB
    __shared__ float s_red[4][128];
    __shared__ float e_lds[128];
    __shared__ float redm[4];
    __shared__ float redl[4];

    // wave w stages its own 64-u slice (hi+lo) for k-chunk k0 into buffer bf: 8 gl_lds ops
    auto stage_b = [&](int bf, int k0) {
#pragma unroll
        for (int hl = 0; hl < 2; ++hl) {
            const unsigned short* base = hl ? w1t_lo : w1t_hi;
#pragma unroll
            for (int ct = 0; ct < 2; ++ct) {
#pragma unroll
                for (int h = 0; h < 2; ++h) {
                    const unsigned short* g =
                        base + (size_t)(w * 64 + ct * 32 + lr) * D_ + k0 + h * 16 + lk * 8;
                    __builtin_amdgcn_global_load_lds(
                        (const __attribute__((address_space(1))) void*)g,
                        (__attribute__((address_space(3))) void*)&bB[bf][w][hl][ct][h][0],
                        16, 0, 0);
                }
            }
        }
    };

    f32x16 acc[4][2] = {};
    const float* aptr = value + ((size_t)b * T_ + t0 + lr) * D_ + lk * 8;

    // prologue: stage(buf0, k=0) FIRST (oldest), then A(0) (16 float4 loads)
    stage_b(0, 0);
    float4 a[4][4];
#pragma unroll
    for (int rt = 0; rt < 4; ++rt) {
#pragma unroll
        for (int h = 0; h < 2; ++h) {
            a[rt][h * 2]     = *reinterpret_cast<const float4*>(aptr + rt * 32 * D_ + h * 16);
            a[rt][h * 2 + 1] = *reinterpret_cast<const float4*>(aptr + rt * 32 * D_ + h * 16 + 4);
        }
    }

    int cur = 0;
    for (int k = 0; k < 8; ++k) {
        const int k0 = k << 5;
        VMCNT(16);                         // own stage(cur) retired; A-loads keep flying
        if (k < 7) stage_b(cur ^ 1, k0 + 32);
        __builtin_amdgcn_s_setprio(1);
#pragma unroll
        for (int rt = 0; rt < 4; ++rt) {
#pragma unroll
            for (int h = 0; h < 2; ++h) {
                bf16x8 ah, al;
                cvt8v(a[rt][h * 2], a[rt][h * 2 + 1], ah, al);   // compiler waits A here
                if (h == 1 && k < 7) {
                    // last use of a[rt] for this k: reload for k+1 (WAR, lands under MFMAs)
#pragma unroll
                    for (int hh = 0; hh < 2; ++hh) {
                        a[rt][hh * 2]     = *reinterpret_cast<const float4*>(
                            aptr + rt * 32 * D_ + k0 + 32 + hh * 16);
                        a[rt][hh * 2 + 1] = *reinterpret_cast<const float4*>(
                            aptr + rt * 32 * D_ + k0 + 32 + hh * 16 + 4);
                    }
                }
#pragma unroll
                for (int ct = 0; ct < 2; ++ct) {
                    const bf16x8 bh = *reinterpret_cast<const bf16x8*>(&bB[cur][w][0][ct][h][lane * 8]);
                    const bf16x8 bl = *reinterpret_cast<const bf16x8*>(&bB[cur][w][1][ct][h][lane * 8]);
                    acc[rt][ct] = mfma32(ah, bh, acc[rt][ct]);
                    acc[rt][ct] = mfma32(al, bh, acc[rt][ct]);
                    acc[rt][ct] = mfma32(ah, bl, acc[rt][ct]);
                }
            }
        }
        __builtin_amdgcn_s_setprio(0);
        cur ^= 1;
    }

    // ---- epilogue: tanh + dot V; reduce over this wave's 64 u (32 lanes = one ct-col set) ----
    float hv2[2], vw2[2];
#pragma unroll
    for (int ct = 0; ct < 2; ++ct) {
        const int u = w * 64 + ct * 32 + lr;
        hv2[ct] = hidden[b * U_ + u];
        vw2[ct] = Vv[u];
    }
#pragma unroll
    for (int rt = 0; rt < 4; ++rt) {
#pragma unroll
        for (int reg = 0; reg < 16; ++reg) {
            float p = 0.f;
#pragma unroll
            for (int ct = 0; ct < 2; ++ct) {
                const float z = acc[rt][ct][reg] + hv2[ct];
                const float e = __expf(2.f * z);
                p += (1.f - __fdividef(2.f, e + 1.f)) * vw2[ct];
            }
            p += __shfl_xor(p, 1, 64);
            p += __shfl_xor(p, 2, 64);
            p += __shfl_xor(p, 4, 64);
            p += __shfl_xor(p, 8, 64);
            p += __shfl_xor(p, 16, 64);
            if (lr == 0)
                s_red[w][rt * 32 + (reg & 3) + 8 * (reg >> 2) + 4 * lk] = p;
        }
    }
    __syncthreads();

    // ---- chunk softmax (max, sum) over the 128 local scores (sum the 4 wave-partials) ----
    float x = (tid < 128) ? (s_red[0][tid] + s_red[1][tid] + s_red[2][tid] + s_red[3][tid])
                          : -3e38f;
    float xm = x;
#pragma unroll
    for (int m = 1; m < 64; m <<= 1) xm = fmaxf(xm, __shfl_xor(xm, m, 64));
    if (lane == 0) redm[w] = xm;
    __syncthreads();
    const float mc = fmaxf(fmaxf(redm[0], redm[1]), fmaxf(redm[2], redm[3]));

    float e = 0.f;
    if (tid < 128) {
        e = __expf(x - mc);
        e_lds[tid] = e;
    }
    float l = e;
#pragma unroll
    for (int m = 1; m < 64; m <<= 1) l += __shfl_xor(l, m, 64);
    if (lane == 0) redl[w] = l;
    __syncthreads();
    const float lc = redl[0] + redl[1] + redl[2] + redl[3];

    // ---- chunk context: ctx[d] = sum_t e_t * value[t][d]  (rows are L2/L3-hot) ----
    const float* vb = value + ((size_t)b * T_ + t0) * D_ + tid;
    float ca0 = 0.f, ca1 = 0.f;
#pragma unroll 8
    for (int t = 0; t < 128; t += 2) {
        ca0 += e_lds[t]     * vb[(size_t)t * D_];
        ca1 += e_lds[t + 1] * vb[(size_t)(t + 1) * D_];
    }
    partial[((size_t)b * 64 + bx) * D_ + tid] = ca0 + ca1;
    if (tid == 0) {
        mstat[b * 64 + bx] = mc;
        lstat[b * 64 + bx] = lc;
    }
}

// ---------------- Kernel 3: cross-chunk softmax merge ----------------
__global__ __launch_bounds__(256) void combine_kernel(const float* __restrict__ partial,
                                                      const float* __restrict__ mstat,
                                                      const float* __restrict__ lstat,
                                                      float* __restrict__ out) {
    const int b = blockIdx.x;
    const int d = threadIdx.x;
    float M = -3e38f;
#pragma unroll 8
    for (int c = 0; c < 64; ++c) M = fmaxf(M, mstat[b * 64 + c]);
    float L = 0.f, a = 0.f;
#pragma unroll 4
    for (int c = 0; c < 64; ++c) {
        const float s = __expf(mstat[b * 64 + c] - M);
        L += lstat[b * 64 + c] * s;
        a += s * partial[((size_t)b * 64 + c) * D_ + d];
    }
    out[b * D_ + d] = a / L;
}

extern "C" void kernel_launch(void* const* d_in, const int* in_sizes, int n_in,
                              void* d_out, int out_size, void* d_ws, size_t ws_size,
                              hipStream_t stream) {
    const float* q     = (const float*)d_in[0];
    const float* value = (const float*)d_in[1];
    const float* W1    = (const float*)d_in[2];
    const float* W2    = (const float*)d_in[3];
    const float* Vv    = (const float*)d_in[4];
    float* out = (float*)d_out;

    char* ws = (char*)d_ws;
    unsigned short* w1t_hi  = (unsigned short*)(ws);                  // 131072 B
    unsigned short* w1t_lo  = (unsigned short*)(ws + 131072);         // 131072 B
    float*          hidden  = (float*)(ws + 262144);                  //  16384 B
    float*          partial = (float*)(ws + 278528);                  // 1048576 B
    float*          mstat   = (float*)(ws + 1327104);                 //   4096 B
    float*          lstat   = (float*)(ws + 1331200);                 //   4096 B

    prep_w1t_kernel<<<dim3(256), dim3(256), 0, stream>>>(W1, w1t_hi, w1t_lo);
    hidden_kernel<<<dim3(B_), dim3(256), 0, stream>>>(q, W2, hidden);

    dim3 g2(T_ / 128, B_);
    scores_ctx_kernel<<<g2, dim3(256), 0, stream>>>(value, w1t_hi, w1t_lo, Vv, hidden,
                                                    partial, mstat, lstat);

    combine_kernel<<<dim3(B_), dim3(256), 0, stream>>>(partial, mstat, lstat, out);
}